// Round 6
// baseline (293.036 us; speedup 1.0000x reference)
//
#include <hip/hip_runtime.h>
#include <stdint.h>

#define D_IN   4096
#define D_OUT  4096
#define NTOK   4096
#define NW     (D_OUT * D_IN)          // 16777216
#define RANK1  15099493u               // floor(0.9f * (NW-1)) as jax computes in f32
#define CAP    1500000                 // candidate list capacity (expected ~450K)

typedef unsigned int  uint32;
typedef unsigned short ushort_t;
typedef float  f32x4  __attribute__((ext_vector_type(4)));
typedef __bf16 bf16x8 __attribute__((ext_vector_type(8)));

// ---------- helpers ----------
__device__ __forceinline__ uint32 rne_bf16(float f) {
  uint32 u = __float_as_uint(f);
  return (u + 0x7FFFu + ((u >> 16) & 1u)) >> 16;
}

__device__ __forceinline__ void gload_lds16(const void* g, void* l) {
  __builtin_amdgcn_global_load_lds((__attribute__((address_space(1))) void*)(g),
                                   (__attribute__((address_space(3))) void*)(l), 16, 0, 0);
}

// block-redundant select: find bin containing `rank` in NB-bin global histogram.
template <int NB>
__device__ __forceinline__ void dsel(const uint32* __restrict__ h, uint32 rank,
                                     uint32* res, uint32* wtot) {
  constexpr int PER = NB >> 8;
  int tid = threadIdx.x;
  int lane = tid & 63, wid = tid >> 6;
  uint32 loc[PER];
  uint32 s = 0;
  int base = tid * PER;
#pragma unroll
  for (int i = 0; i < PER; i++) { loc[i] = h[base + i]; s += loc[i]; }
  uint32 v = s;
  for (int d = 1; d < 64; d <<= 1) { uint32 o = __shfl_up(v, (unsigned)d); if (lane >= d) v += o; }
  if (lane == 63) wtot[wid] = v;
  __syncthreads();
  uint32 woff = 0;
  for (int w = 0; w < wid; w++) woff += wtot[w];
  uint32 incl = v + woff, excl = incl - s;
  if (rank >= excl && rank < incl) {
    uint32 c = excl;
#pragma unroll
    for (int i = 0; i < PER; i++) {
      if (rank < c + loc[i]) { res[0] = (uint32)(base + i); res[1] = rank - c; break; }
      c += loc[i];
    }
  }
  __syncthreads();
}

// ---------- K1: hist pass 1 (blocks 0..2047) fused with convert_x (blocks 2048..3071) ----------
__global__ void k1_hist1_convx(const uint4* __restrict__ wb, uint32* __restrict__ hist,
                               const float4* __restrict__ x, uint4* __restrict__ xout) {
  __shared__ uint32 lh[4][2048];
  if (blockIdx.x < 2048) {
    for (int i = threadIdx.x; i < 8192; i += 256) ((uint32*)lh)[i] = 0;
    __syncthreads();
    int wid = threadIdx.x >> 6;
    int idx = blockIdx.x * 256 + threadIdx.x;
    for (int i = idx; i < NW / 4; i += 2048 * 256) {
      uint4 v = wb[i];
      atomicAdd(&lh[wid][(v.x & 0x7FFFFFFFu) >> 20], 1u);
      atomicAdd(&lh[wid][(v.y & 0x7FFFFFFFu) >> 20], 1u);
      atomicAdd(&lh[wid][(v.z & 0x7FFFFFFFu) >> 20], 1u);
      atomicAdd(&lh[wid][(v.w & 0x7FFFFFFFu) >> 20], 1u);
    }
    __syncthreads();
    for (int i = threadIdx.x; i < 2048; i += 256) {
      uint32 c = lh[0][i] + lh[1][i] + lh[2][i] + lh[3][i];
      if (c) atomicAdd(&hist[i], c);
    }
  } else {
    int i = (blockIdx.x - 2048) * 256 + threadIdx.x;
    for (; i < NW / 8; i += 1024 * 256) {
      float4 a = x[2 * i], b = x[2 * i + 1];
      uint4 o;
      o.x = rne_bf16(a.x) | (rne_bf16(a.y) << 16);
      o.y = rne_bf16(a.z) | (rne_bf16(a.w) << 16);
      o.z = rne_bf16(b.x) | (rne_bf16(b.y) << 16);
      o.w = rne_bf16(b.z) | (rne_bf16(b.w) << 16);
      xout[i] = o;
    }
  }
}

// ---------- K2: decide + convert W + compact threshold-bin candidates (ONE pass) ----------
__global__ void k2_decide(const float4* __restrict__ w, const uint32* __restrict__ hist1,
                          uint4* __restrict__ out, uint2* __restrict__ cand,
                          uint32* __restrict__ cnt) {
  __shared__ uint32 res1[2], wt[4];
  __shared__ uint32 lcnt, lbase;
  __shared__ uint2 lbuf[3072];
  if (threadIdx.x == 0) lcnt = 0;
  dsel<2048>(hist1, RANK1, res1, wt);          // syncs internally
  uint32 bstar = res1[0];
  int i = blockIdx.x * 256 + threadIdx.x;
  for (; i < NW / 8; i += 512 * 256) {
    float4 a = w[2 * i], b = w[2 * i + 1];
    float f[8] = {a.x, a.y, a.z, a.w, b.x, b.y, b.z, b.w};
    uint32 h[8];
#pragma unroll
    for (int j = 0; j < 8; j++) {
      uint32 bits = __float_as_uint(f[j]);
      uint32 bin = (bits & 0x7FFFFFFFu) >> 20;
      h[j] = (bin > bstar) ? rne_bf16(f[j]) : 0u;
      if (bin == bstar) {
        uint32 p = atomicAdd(&lcnt, 1u);
        if (p < 3072) lbuf[p] = make_uint2((uint32)(8 * i + j), bits);
      }
    }
    uint4 o;
    o.x = h[0] | (h[1] << 16);
    o.y = h[2] | (h[3] << 16);
    o.z = h[4] | (h[5] << 16);
    o.w = h[6] | (h[7] << 16);
    out[i] = o;
  }
  __syncthreads();
  if (threadIdx.x == 0) lbase = atomicAdd(cnt, lcnt);
  __syncthreads();
  for (uint32 p = threadIdx.x; p < lcnt && p < 3072; p += 256) {
    uint32 g = lbase + p;
    if (g < CAP) cand[g] = lbuf[p];
  }
}

// ---------- S1: 1024-bin hist over candidate mag bits [19:10] ----------
__global__ void s1_hist(const uint2* __restrict__ cand, const uint32* __restrict__ cnt,
                        uint32* __restrict__ hs1) {
  __shared__ uint32 lh[1024];
  for (int i = threadIdx.x; i < 1024; i += 256) lh[i] = 0;
  __syncthreads();
  uint32 n = *cnt; if (n > CAP) n = CAP;
  for (uint32 i = blockIdx.x * 256 + threadIdx.x; i < n; i += gridDim.x * 256) {
    uint32 mag = cand[i].y & 0x7FFFFFFFu;
    atomicAdd(&lh[(mag >> 10) & 1023u], 1u);
  }
  __syncthreads();
  for (int i = threadIdx.x; i < 1024; i += 256) if (lh[i]) atomicAdd(&hs1[i], lh[i]);
}

// ---------- S2: filter on bits[19:10], hist bits [9:0] ----------
__global__ void s2_hist(const uint2* __restrict__ cand, const uint32* __restrict__ cnt,
                        const uint32* __restrict__ hist1, const uint32* __restrict__ hs1,
                        uint32* __restrict__ hs2) {
  __shared__ uint32 lh[1024];
  __shared__ uint32 res1[2], res2[2], wt[4];
  for (int i = threadIdx.x; i < 1024; i += 256) lh[i] = 0;
  dsel<2048>(hist1, RANK1, res1, wt);
  dsel<1024>(hs1, res1[1], res2, wt);
  uint32 b2 = res2[0];
  uint32 n = *cnt; if (n > CAP) n = CAP;
  for (uint32 i = blockIdx.x * 256 + threadIdx.x; i < n; i += gridDim.x * 256) {
    uint32 mag = cand[i].y & 0x7FFFFFFFu;
    if (((mag >> 10) & 1023u) == b2) atomicAdd(&lh[mag & 1023u], 1u);
  }
  __syncthreads();
  for (int i = threadIdx.x; i < 1024; i += 256) if (lh[i]) atomicAdd(&hs2[i], lh[i]);
}

// ---------- K5: final threshold, fix up kept candidates ----------
__global__ void k5_fixup(const uint2* __restrict__ cand, const uint32* __restrict__ cnt,
                         const uint32* __restrict__ hist1, const uint32* __restrict__ hs1,
                         const uint32* __restrict__ hs2, ushort_t* __restrict__ wb) {
  __shared__ uint32 res1[2], res2[2], res3[2], wt[4];
  dsel<2048>(hist1, RANK1, res1, wt);
  dsel<1024>(hs1, res1[1], res2, wt);
  dsel<1024>(hs2, res2[1], res3, wt);
  uint32 thr_mag = (res1[0] << 20) | (res2[0] << 10) | res3[0];
  uint32 n = *cnt; if (n > CAP) n = CAP;
  for (uint32 i = blockIdx.x * 256 + threadIdx.x; i < n; i += gridDim.x * 256) {
    uint2 c = cand[i];
    uint32 mag = c.y & 0x7FFFFFFFu;
    if (mag > thr_mag) wb[c.x] = (ushort_t)rne_bf16(__uint_as_float(c.y));
  }
}

// ---------- GEMM: C[M,N] = Xb[M,K] * Wb[N,K]^T + bias ----------
// 256x256 tile, BK=32, 8 waves (2x4). A staged in quad-buffered LDS (64KB,
// shared by 4 waves); B loaded DIRECTLY global->VGPR per wave (double-buffered,
// no barrier, L2-served) -- cuts CU LDS traffic 96KB->64KB per K-tile so the
// LDS pipe (753 cyc) fits under the MFMA pipe (1241 cyc). One barrier + one
// counted vmcnt(2) per K-tile; a03(t+1) pre-read before the barrier.
#define TILES 128

#define MF16(AF, BF, MO)                                                                          \
  acc[(MO)+0][0] = __builtin_amdgcn_mfma_f32_16x16x32_bf16(AF[0], BF[0], acc[(MO)+0][0], 0,0,0);  \
  acc[(MO)+0][1] = __builtin_amdgcn_mfma_f32_16x16x32_bf16(AF[0], BF[1], acc[(MO)+0][1], 0,0,0);  \
  acc[(MO)+0][2] = __builtin_amdgcn_mfma_f32_16x16x32_bf16(AF[0], BF[2], acc[(MO)+0][2], 0,0,0);  \
  acc[(MO)+0][3] = __builtin_amdgcn_mfma_f32_16x16x32_bf16(AF[0], BF[3], acc[(MO)+0][3], 0,0,0);  \
  acc[(MO)+1][0] = __builtin_amdgcn_mfma_f32_16x16x32_bf16(AF[1], BF[0], acc[(MO)+1][0], 0,0,0);  \
  acc[(MO)+1][1] = __builtin_amdgcn_mfma_f32_16x16x32_bf16(AF[1], BF[1], acc[(MO)+1][1], 0,0,0);  \
  acc[(MO)+1][2] = __builtin_amdgcn_mfma_f32_16x16x32_bf16(AF[1], BF[2], acc[(MO)+1][2], 0,0,0);  \
  acc[(MO)+1][3] = __builtin_amdgcn_mfma_f32_16x16x32_bf16(AF[1], BF[3], acc[(MO)+1][3], 0,0,0);  \
  acc[(MO)+2][0] = __builtin_amdgcn_mfma_f32_16x16x32_bf16(AF[2], BF[0], acc[(MO)+2][0], 0,0,0);  \
  acc[(MO)+2][1] = __builtin_amdgcn_mfma_f32_16x16x32_bf16(AF[2], BF[1], acc[(MO)+2][1], 0,0,0);  \
  acc[(MO)+2][2] = __builtin_amdgcn_mfma_f32_16x16x32_bf16(AF[2], BF[2], acc[(MO)+2][2], 0,0,0);  \
  acc[(MO)+2][3] = __builtin_amdgcn_mfma_f32_16x16x32_bf16(AF[2], BF[3], acc[(MO)+2][3], 0,0,0);  \
  acc[(MO)+3][0] = __builtin_amdgcn_mfma_f32_16x16x32_bf16(AF[3], BF[0], acc[(MO)+3][0], 0,0,0);  \
  acc[(MO)+3][1] = __builtin_amdgcn_mfma_f32_16x16x32_bf16(AF[3], BF[1], acc[(MO)+3][1], 0,0,0);  \
  acc[(MO)+3][2] = __builtin_amdgcn_mfma_f32_16x16x32_bf16(AF[3], BF[2], acc[(MO)+3][2], 0,0,0);  \
  acc[(MO)+3][3] = __builtin_amdgcn_mfma_f32_16x16x32_bf16(AF[3], BF[3], acc[(MO)+3][3], 0,0,0);

// Body for tile T. S = T&1, SN = (T+1)&1 (literals).
#define GBODY2(T, S, SN)                                                       \
  {                                                                            \
    /* B(T+1) frag loads -> regs (4 vm ops) */                                 \
    bq[SN][0] = *(const bf16x8*)pB0v;                                          \
    bq[SN][1] = *(const bf16x8*)pB1v;                                          \
    bq[SN][2] = *(const bf16x8*)pB2v;                                          \
    bq[SN][3] = *(const bf16x8*)pB3v;                                          \
    __builtin_amdgcn_sched_barrier(0);                                         \
    /* stage A(T+2) (2 vm ops) */                                              \
    ushort_t* sb = lds + (((T) + 2) & 3) * 8192;                               \
    gload_lds16(pA0, sb + ld0);                                                \
    gload_lds16(pA1, sb + ld1);                                                \
    __builtin_amdgcn_sched_barrier(0);                                         \
    /* a47(T) reads */                                                         \
    const bf16x8* A8c = (const bf16x8*)(lds + ((T) & 3) * 8192);               \
    a47[0] = A8c[(ar +  64) * 4 + csel];                                       \
    a47[1] = A8c[(ar +  80) * 4 + csel];                                       \
    a47[2] = A8c[(ar +  96) * 4 + csel];                                       \
    a47[3] = A8c[(ar + 112) * 4 + csel];                                       \
    __builtin_amdgcn_sched_barrier(0);                                         \
    asm volatile("s_waitcnt lgkmcnt(4)" ::: "memory");   /* a03(T) landed */   \
    __builtin_amdgcn_sched_barrier(0);                                         \
    __builtin_amdgcn_s_setprio(1);                                             \
    MF16(a03[S], bq[S], 0)                                                     \
    __builtin_amdgcn_s_setprio(0);                                             \
    __builtin_amdgcn_sched_barrier(0);                                         \
    asm volatile("s_waitcnt lgkmcnt(0)" ::: "memory");   /* a47(T) landed */   \
    __builtin_amdgcn_sched_barrier(0);                                         \
    __builtin_amdgcn_s_setprio(1);                                             \
    MF16(a47, bq[S], 4)                                                        \
    __builtin_amdgcn_s_setprio(0);                                             \
    __builtin_amdgcn_sched_barrier(0);                                         \
    /* B(T+1) + A(T+1) landed; A(T+2) may stay in flight */                    \
    asm volatile("s_waitcnt vmcnt(2)" ::: "memory");                           \
    __builtin_amdgcn_sched_barrier(0);                                         \
    /* pre-read a03(T+1) before the barrier */                                 \
    const bf16x8* A8n = (const bf16x8*)(lds + (((T) + 1) & 3) * 8192);         \
    a03[SN][0] = A8n[(ar +  0) * 4 + csel];                                    \
    a03[SN][1] = A8n[(ar + 16) * 4 + csel];                                    \
    a03[SN][2] = A8n[(ar + 32) * 4 + csel];                                    \
    a03[SN][3] = A8n[(ar + 48) * 4 + csel];                                    \
    __builtin_amdgcn_sched_barrier(0);                                         \
    asm volatile("s_barrier" ::: "memory");                                    \
    if ((T) < TILES - 3) { pA0 += 32; pA1 += 32; }                             \
    if ((T) < TILES - 2) { pB0v += 32; pB1v += 32; pB2v += 32; pB3v += 32; }   \
  }

__global__ __launch_bounds__(512, 2) void gemm_bt(const ushort_t* __restrict__ A,
                                                  const ushort_t* __restrict__ B,
                                                  const float* __restrict__ bias,
                                                  float* __restrict__ C) {
  extern __shared__ ushort_t lds[];   // 4 bufs x 16KB (A only) = 64KB

  int bid = blockIdx.x;                     // 256 blocks
  int swz = (bid & 7) * 32 + (bid >> 3);    // bijective XCD swizzle
  int bm = swz >> 4;
  int bn = swz & 15;

  int tid  = threadIdx.x;
  int lane = tid & 63;
  int wave = tid >> 6;
  int wm = wave >> 2, wn = wave & 3;        // 2x4 wave grid: 128x64 per wave

  int l15  = lane & 15;
  int kq   = lane >> 4;
  int csel = kq ^ ((lane >> 1) & 3);        // LDS bank swizzle (A only)

  // A staging geometry (16KB panel = 1024 chunks; 2 per thread)
  int idx0 = tid, idx1 = 512 + tid;
  int sr0 = idx0 >> 2, scl0 = (idx0 & 3) ^ ((sr0 >> 1) & 3);
  int sr1 = idx1 >> 2, scl1 = (idx1 & 3) ^ ((sr1 >> 1) & 3);
  int ld0 = idx0 * 8, ld1 = idx1 * 8;
  const ushort_t* pA0 = A + (size_t)(bm * 256 + sr0) * D_IN + scl0 * 8;
  const ushort_t* pA1 = A + (size_t)(bm * 256 + sr1) * D_IN + scl1 * 8;

  // B direct-load pointers (per-lane, 4 rows per wave), start at k=32 (tile 1)
  int brow = bn * 256 + wn * 64 + l15;
  const ushort_t* pB0v = B + (size_t)(brow +  0) * D_IN + kq * 8 + 32;
  const ushort_t* pB1v = B + (size_t)(brow + 16) * D_IN + kq * 8 + 32;
  const ushort_t* pB2v = B + (size_t)(brow + 32) * D_IN + kq * 8 + 32;
  const ushort_t* pB3v = B + (size_t)(brow + 48) * D_IN + kq * 8 + 32;

  f32x4 acc[8][4];
#pragma unroll
  for (int m = 0; m < 8; m++)
#pragma unroll
    for (int n = 0; n < 4; n++) acc[m][n] = (f32x4){0.f, 0.f, 0.f, 0.f};

  bf16x8 bq[2][4], a03[2][4], a47[4];

  // prologue: issue A(0), B(0), A(1)  [FIFO order matters for vmcnt(2)]
  gload_lds16(pA0, lds + ld0);
  gload_lds16(pA1, lds + ld1);
  __builtin_amdgcn_sched_barrier(0);
  bq[0][0] = *(const bf16x8*)(pB0v - 32);
  bq[0][1] = *(const bf16x8*)(pB1v - 32);
  bq[0][2] = *(const bf16x8*)(pB2v - 32);
  bq[0][3] = *(const bf16x8*)(pB3v - 32);
  __builtin_amdgcn_sched_barrier(0);
  gload_lds16(pA0 + 32, lds + 8192 + ld0);
  gload_lds16(pA1 + 32, lds + 8192 + ld1);
  pA0 += 64; pA1 += 64;                      // in-loop staging starts at tile 2
  __builtin_amdgcn_sched_barrier(0);
  asm volatile("s_waitcnt vmcnt(2)" ::: "memory");   // A(0)+B(0) landed
  asm volatile("s_barrier" ::: "memory");

  int ar = wm * 128 + l15;

  // pre-read a03(0)
  {
    const bf16x8* A8 = (const bf16x8*)lds;
    a03[0][0] = A8[(ar +  0) * 4 + csel];
    a03[0][1] = A8[(ar + 16) * 4 + csel];
    a03[0][2] = A8[(ar + 32) * 4 + csel];
    a03[0][3] = A8[(ar + 48) * 4 + csel];
    __builtin_amdgcn_sched_barrier(0);
  }

  // tiles 0..126
  for (int tt = 0; tt < 63; tt++) {
    GBODY2(2 * tt,     0, 1)
    GBODY2(2 * tt + 1, 1, 0)
  }
  GBODY2(126, 0, 1)

  // tail: tile 127 (S=1), no more loads
  {
    const bf16x8* A8c = (const bf16x8*)(lds + (127 & 3) * 8192);
    a47[0] = A8c[(ar +  64) * 4 + csel];
    a47[1] = A8c[(ar +  80) * 4 + csel];
    a47[2] = A8c[(ar +  96) * 4 + csel];
    a47[3] = A8c[(ar + 112) * 4 + csel];
    __builtin_amdgcn_sched_barrier(0);
    asm volatile("s_waitcnt lgkmcnt(4)" ::: "memory");
    __builtin_amdgcn_sched_barrier(0);
    __builtin_amdgcn_s_setprio(1);
    MF16(a03[1], bq[1], 0)
    __builtin_amdgcn_s_setprio(0);
    asm volatile("s_waitcnt lgkmcnt(0)" ::: "memory");
    __builtin_amdgcn_sched_barrier(0);
    __builtin_amdgcn_s_setprio(1);
    MF16(a47, bq[1], 4)
    __builtin_amdgcn_s_setprio(0);
  }

  int orow0 = bm * 256 + wm * 128 + (lane >> 4) * 4;
  int ocol0 = bn * 256 + wn * 64 + l15;
#pragma unroll
  for (int n = 0; n < 4; n++) {
    float bb = bias[ocol0 + n * 16];
#pragma unroll
    for (int m = 0; m < 8; m++) {
#pragma unroll
      for (int r = 0; r < 4; r++) {
        C[(size_t)(orow0 + m * 16 + r) * D_OUT + ocol0 + n * 16] = acc[m][n][r] + bb;
      }
    }
  }
}

// ---------- launch ----------
extern "C" void kernel_launch(void* const* d_in, const int* in_sizes, int n_in,
                              void* d_out, int out_size, void* d_ws, size_t ws_size,
                              hipStream_t stream) {
  const float* x = (const float*)d_in[0];
  const float* w = (const float*)d_in[1];
  const float* bias = (const float*)d_in[2];
  float* out = (float*)d_out;

  char* ws = (char*)d_ws;
  uint32* hist1 = (uint32*)ws;                       // 2048 bins @ 0
  uint32* hs1   = (uint32*)(ws + 8192);              // 1024 bins
  uint32* hs2   = (uint32*)(ws + 12288);             // 1024 bins
  uint32* cnt   = (uint32*)(ws + 16384);             // 1 word
  ushort_t* Xb  = (ushort_t*)(ws + 65536);
  ushort_t* Wb  = (ushort_t*)(ws + 65536 + (size_t)NW * 2);
  uint2*   cand = (uint2*)(ws + 65536 + (size_t)NW * 4);

  hipMemsetAsync(d_ws, 0, 16448, stream);

  k1_hist1_convx<<<3072, 256, 0, stream>>>((const uint4*)w, hist1, (const float4*)x, (uint4*)Xb);
  k2_decide<<<512, 256, 0, stream>>>((const float4*)w, hist1, (uint4*)Wb, cand, cnt);
  s1_hist<<<128, 256, 0, stream>>>(cand, cnt, hs1);
  s2_hist<<<128, 256, 0, stream>>>(cand, cnt, hist1, hs1, hs2);
  k5_fixup<<<256, 256, 0, stream>>>(cand, cnt, hist1, hs1, hs2, Wb);

  gemm_bt<<<256, 512, 65536, stream>>>(Xb, Wb, bias, out);
}